// Round 1
// baseline (290.125 us; speedup 1.0000x reference)
//
#include <hip/hip_runtime.h>
#include <hip/hip_bf16.h>

// Problem: B=1, H=16, S=2048, KV=4096, D=64
//   qk = (Q @ K^T) * (1/8) + structured_mask(0/1, ADDITIVE)
//   attn = softmax(qk, axis=-1)
//   attn = where(drop_mask, attn * keep_scale, 0)      (post-softmax dropout)
//   out  = attn @ V                                     (f32 out)
//
// out[q][d] = (KEEP_SCALE / sum_k p_k) * sum_k (drop_k * p_k * V[k][d]),
//   p_k = exp(s_k - m),  denominator uses ALL k (no dropout).

#define H_   16
#define S_   2048
#define KV_  4096
#define D_   64
#define KVC  64

using bf16x8 = __attribute__((ext_vector_type(8))) __bf16;
using bf16x4 = __attribute__((ext_vector_type(4))) __bf16;
using f32x4  = __attribute__((ext_vector_type(4))) float;
using uint4v = __attribute__((ext_vector_type(4))) unsigned;

constexpr float KEEP_SCALE = (float)(1.0 / (1.0 - 0.31881923790897965));

// ---------------------------------------------------------------------------
// Detect drop_mask storage: 4-byte elements (int32 0/1 or f32 0.0/1.0) vs
// 1-byte bool. Scan first 4096 words (16 KB — safe for every candidate size).
// If every word is in {0, 1, 0x3F800000} -> word mode (flag=0), else byte
// mode (flag=1). 16384 random 0/1 BYTES can never all parse as such words.
// Deterministic (pure function of input) -> graph-capture safe.
// ---------------------------------------------------------------------------
__global__ void detect_mask(const unsigned* __restrict__ m, int* __restrict__ flag) {
    __shared__ int bad;
    if (threadIdx.x == 0) bad = 0;
    __syncthreads();
    int ok = 1;
    for (int i = threadIdx.x; i < 4096; i += blockDim.x) {
        unsigned w = m[i];
        if (w > 1u && w != 0x3F800000u) ok = 0;
    }
    if (!ok) atomicOr(&bad, 1);
    __syncthreads();
    if (threadIdx.x == 0) *flag = bad;
}

// ---------------------------------------------------------------------------
// Flash attention, 4 waves/block, 16 q-rows per wave, KV chunk = 64.
// Swapped QK^T: S^T = mfma(K, Q) so each lane's softmax row is q = lane&15.
// ---------------------------------------------------------------------------
__global__ __launch_bounds__(256, 2)
void attn_fwd(const float* __restrict__ Q, const float* __restrict__ K,
              const float* __restrict__ V, const unsigned char* __restrict__ Mb,
              const int* __restrict__ flagp, float* __restrict__ Out)
{
    __shared__ __bf16 Kb[KVC][72];      // [kv][d]  +8 pad (16B-aligned rows)
    __shared__ __bf16 Vt[D_][72];       // [d][kv]  transposed V chunk
    __shared__ __bf16 Pb[4][16][72];    // per-wave P tile [q][kv]

    const int tid  = threadIdx.x;
    const int wave = tid >> 6;
    const int lane = tid & 63;
    const int lq   = lane & 15;   // q index within wave tile (S^T col)
    const int g    = lane >> 4;   // lane group 0..3

    // XCD-aware bijective swizzle (512 blocks, 512 % 8 == 0)
    const int bid = blockIdx.x;
    const int wg  = (bid & 7) * 64 + (bid >> 3);
    const int h   = wg >> 5;      // head
    const int qb  = wg & 31;      // q block (64 rows)
    const int q0  = qb * 64 + wave * 16;

    const float* Qh = Q + ((size_t)h * S_ + q0) * D_;
    const float* Kh = K + (size_t)h * KV_ * D_;
    const float* Vh = V + (size_t)h * KV_ * D_;
    const bool byteMode = (*flagp != 0);

    // --- Q fragments (B-operand of swapped QK^T): lane holds Q[q0+lq][g*8 + 32*kk + 0..7]
    bf16x8 bq[2];
    {
        const float* qrow = Qh + lq * D_ + g * 8;
        #pragma unroll
        for (int kk = 0; kk < 2; ++kk) {
            f32x4 f0 = *(const f32x4*)(qrow + 32 * kk);
            f32x4 f1 = *(const f32x4*)(qrow + 32 * kk + 4);
            bf16x8 b;
            #pragma unroll
            for (int e = 0; e < 4; ++e) { b[e] = (__bf16)f0[e]; b[4 + e] = (__bf16)f1[e]; }
            bq[kk] = b;
        }
    }

    const int q_g = q0 + lq;  // this lane's global query row (softmax state row)
    const unsigned char* mrowB = Mb + ((size_t)h * S_ + q_g) * KV_;
    const unsigned*      mrowW = (const unsigned*)Mb + ((size_t)h * S_ + q_g) * KV_;

    float mrun = -INFINITY, lrun = 0.f;
    f32x4 acc[4] = {};   // out rows g*4+i, cols nt*16+lq

    // staging: thread -> row sr (0..63), col group sc (16 floats)
    const int sr = tid >> 2;
    const int sc = (tid & 3) * 16;

    for (int kvb = 0; kvb < KV_; kvb += KVC) {
        __syncthreads();   // protect Kb/Vt from previous iteration's readers

        // ---- stage K chunk -> Kb (bf16), V chunk -> Vt (bf16, transposed)
        {
            const float* kr = Kh + (size_t)(kvb + sr) * D_ + sc;
            #pragma unroll
            for (int j = 0; j < 2; ++j) {
                f32x4 f0 = ((const f32x4*)kr)[2 * j];
                f32x4 f1 = ((const f32x4*)kr)[2 * j + 1];
                bf16x8 b;
                #pragma unroll
                for (int e = 0; e < 4; ++e) { b[e] = (__bf16)f0[e]; b[4 + e] = (__bf16)f1[e]; }
                *(bf16x8*)&Kb[sr][sc + 8 * j] = b;
            }
            const float* vr = Vh + (size_t)(kvb + sr) * D_ + sc;
            #pragma unroll
            for (int j = 0; j < 4; ++j) {
                f32x4 f = ((const f32x4*)vr)[j];
                #pragma unroll
                for (int e = 0; e < 4; ++e) Vt[sc + 4 * j + e][sr] = (__bf16)f[e];
            }
        }
        __syncthreads();

        // ---- QK^T (swapped): S^T tiles; lane holds s for q=q_g, kv = kvb + 16t + 4g + i
        float s[4][4];
        #pragma unroll
        for (int t = 0; t < 4; ++t) {
            f32x4 st = {0.f, 0.f, 0.f, 0.f};
            #pragma unroll
            for (int kk = 0; kk < 2; ++kk) {
                bf16x8 ak = *(const bf16x8*)&Kb[t * 16 + lq][g * 8 + kk * 32];
                st = __builtin_amdgcn_mfma_f32_16x16x32_bf16(ak, bq[kk], st, 0, 0, 0);
            }
            #pragma unroll
            for (int i = 0; i < 4; ++i) {
                const int kvg = kvb + t * 16 + g * 4 + i;
                // additive 0/1 mask: triu(S,S,1) | tril(S,S) concatenated
                const bool one = (kvg < S_) ? (kvg > q_g) : ((kvg - S_) <= q_g);
                s[t][i] = st[i] * 0.125f + (one ? 1.f : 0.f);
            }
        }

        // ---- online softmax (row = q_g, partners: lanes lq, lq+16, lq+32, lq+48)
        float cmax = s[0][0];
        #pragma unroll
        for (int t = 0; t < 4; ++t)
            #pragma unroll
            for (int i = 0; i < 4; ++i) cmax = fmaxf(cmax, s[t][i]);
        cmax = fmaxf(cmax, __shfl_xor(cmax, 16));
        cmax = fmaxf(cmax, __shfl_xor(cmax, 32));

        const float mnew = fmaxf(mrun, cmax);
        const float corr = __expf(mrun - mnew);   // first chunk: exp(-inf)=0
        float p[4][4];
        float psum = 0.f;
        #pragma unroll
        for (int t = 0; t < 4; ++t)
            #pragma unroll
            for (int i = 0; i < 4; ++i) { p[t][i] = __expf(s[t][i] - mnew); psum += p[t][i]; }
        psum += __shfl_xor(psum, 16);
        psum += __shfl_xor(psum, 32);
        lrun = lrun * corr + psum;   // denominator WITHOUT dropout
        mrun = mnew;

        // ---- dropout + write P (bf16) to per-wave LDS tile
        #pragma unroll
        for (int t = 0; t < 4; ++t) {
            const int kcol = kvb + t * 16 + g * 4;
            float pd[4];
            if (byteMode) {
                const unsigned w = *(const unsigned*)(mrowB + kcol);
                #pragma unroll
                for (int i = 0; i < 4; ++i) pd[i] = ((w >> (8 * i)) & 0xFFu) ? p[t][i] : 0.f;
            } else {
                const uint4v w = *(const uint4v*)(mrowW + kcol);
                #pragma unroll
                for (int i = 0; i < 4; ++i) pd[i] = w[i] ? p[t][i] : 0.f;
            }
            bf16x4 pb;
            #pragma unroll
            for (int i = 0; i < 4; ++i) pb[i] = (__bf16)pd[i];
            *(bf16x4*)&Pb[wave][lq][t * 16 + g * 4] = pb;
        }

        // ---- rescale accumulator (acc rows are q = g*4+i; state lives in lane g*4+i)
        #pragma unroll
        for (int i = 0; i < 4; ++i) {
            const float cr = __shfl(corr, g * 4 + i);
            #pragma unroll
            for (int nt = 0; nt < 4; ++nt) acc[nt][i] *= cr;
        }

        // make this wave's Pb writes visible to its own cross-lane reads
        asm volatile("s_waitcnt lgkmcnt(0)" ::: "memory");

        // ---- PV: out += P[16q x 64kv] @ V[64kv x 64d]
        #pragma unroll
        for (int c = 0; c < 2; ++c) {
            bf16x8 ap = *(const bf16x8*)&Pb[wave][lq][c * 32 + g * 8];
            #pragma unroll
            for (int nt = 0; nt < 4; ++nt) {
                bf16x8 bv = *(const bf16x8*)&Vt[nt * 16 + lq][c * 32 + g * 8];
                acc[nt] = __builtin_amdgcn_mfma_f32_16x16x32_bf16(ap, bv, acc[nt], 0, 0, 0);
            }
        }
    }

    // ---- epilogue: out = acc * KEEP_SCALE / l
    float inv[4];
    #pragma unroll
    for (int i = 0; i < 4; ++i) {
        const float lr = __shfl(lrun, g * 4 + i);
        inv[i] = KEEP_SCALE / lr;
    }
    float* orow = Out + ((size_t)h * S_ + q0 + g * 4) * D_;
    #pragma unroll
    for (int i = 0; i < 4; ++i)
        #pragma unroll
        for (int nt = 0; nt < 4; ++nt)
            orow[i * D_ + nt * 16 + lq] = acc[nt][i] * inv[i];
}

extern "C" void kernel_launch(void* const* d_in, const int* in_sizes, int n_in,
                              void* d_out, int out_size, void* d_ws, size_t ws_size,
                              hipStream_t stream) {
    const float* Q = (const float*)d_in[0];
    const float* K = (const float*)d_in[1];
    const float* V = (const float*)d_in[2];
    const unsigned char* M = (const unsigned char*)d_in[3];
    int* flag = (int*)d_ws;

    detect_mask<<<1, 256, 0, stream>>>((const unsigned*)M, flag);
    attn_fwd<<<512, 256, 0, stream>>>(Q, K, V, M, flag, (float*)d_out);
}